// Round 10
// baseline (420.954 us; speedup 1.0000x reference)
//
#include <hip/hip_runtime.h>
#include <math.h>

#define SS   2048
#define HH   2048
#define NH_  32
#define NKV_ 8
#define HD_  64
#define QKVO 3072     // (32 + 2*8) * 64
#define MTOK 4096     // B * S

typedef _Float16 f16x8 __attribute__((ext_vector_type(8)));   // 8 fp16 in 4 VGPRs
typedef float f32x4 __attribute__((ext_vector_type(4)));
typedef int   i32x4 __attribute__((ext_vector_type(4)));      // 16 i8 (A/B frag) or 4 i32 (C/D)

__device__ inline ushort f2h(float f) {
    _Float16 h = (_Float16)f;
    return *(ushort*)&h;
}
__device__ inline int packi8(float a, float b, float c, float d) {   // values are exact ints
    return ((int)a & 255) | (((int)b & 255) << 8) | (((int)c & 255) << 16) | (((int)d & 255) << 24);
}

__device__ inline void gl_lds16(const void* g, void* l) {
    __builtin_amdgcn_global_load_lds((const __attribute__((address_space(1))) void*)g,
                                     (__attribute__((address_space(3))) void*)l, 16, 0, 0);
}

// ---------------- fused prologue: |w| sums (float4) + rope table ----------------
// blocks 0..1535 -> sum|w_qkv|; 1536..2559 -> sum|w_out|; 2560..2815 -> rope table
__global__ __launch_bounds__(256) void prep_kernel(const float* __restrict__ wq,
                                                   const float* __restrict__ wo,
                                                   float* __restrict__ scal,
                                                   float* __restrict__ tab) {
    __shared__ float red[256];
    int bx = blockIdx.x, tid = threadIdx.x;
    if (bx < 2560) {
        const float* src; float* dst; int n4, b0, nb;
        if (bx < 1536) { src = wq; dst = scal + 0; n4 = QKVO * HH / 4; b0 = bx;        nb = 1536; }
        else           { src = wo; dst = scal + 1; n4 = HH * HH / 4;   b0 = bx - 1536; nb = 1024; }
        float acc = 0.f;
        for (int i = b0 * 256 + tid; i < n4; i += nb * 256) {
            float4 v = ((const float4*)src)[i];
            acc += (fabsf(v.x) + fabsf(v.y)) + (fabsf(v.z) + fabsf(v.w));
        }
        red[tid] = acc;
        __syncthreads();
        for (int s = 128; s > 0; s >>= 1) { if (tid < s) red[tid] += red[tid + s]; __syncthreads(); }
        if (tid == 0) atomicAdd(dst, red[0]);
    } else {
        int i = (bx - 2560) * 256 + tid;        // SS*32 threads
        int sp = i >> 5, d = i & 31;
        float inv = (float)pow(10000.0, -(double)d / 32.0);
        float ang = (float)sp * inv;
        tab[sp * 64 + d]      = cosf(ang);
        tab[sp * 64 + 32 + d] = sinf(ang);
    }
}

// ---------------- fused ternary weight quant -> i8 (both weights) ----------------
__global__ __launch_bounds__(256) void wquant_kernel(const float* __restrict__ wq,
                                                     const float* __restrict__ wo,
                                                     int* __restrict__ q1,
                                                     int* __restrict__ q2,
                                                     const float* __restrict__ scal) {
    int bx = blockIdx.x, tid = threadIdx.x;
    const float* src; int* dst; int n4, b0, nb; float mean;
    if (bx < 1536) { src = wq; dst = q1; n4 = QKVO * HH / 4; b0 = bx;        nb = 1536;
                     mean = fmaxf(scal[0] * (1.0f / 6291456.0f), 1e-5f); }
    else           { src = wo; dst = q2; n4 = HH * HH / 4;   b0 = bx - 1536; nb = 1024;
                     mean = fmaxf(scal[1] * (1.0f / 4194304.0f), 1e-5f); }
    float wsc = 1.f / mean;
    for (int i = b0 * 256 + tid; i < n4; i += nb * 256) {
        float4 v = ((const float4*)src)[i];
        dst[i] = packi8(fminf(fmaxf(rintf(v.x * wsc), -1.f), 1.f),
                        fminf(fmaxf(rintf(v.y * wsc), -1.f), 1.f),
                        fminf(fmaxf(rintf(v.z * wsc), -1.f), 1.f),
                        fminf(fmaxf(rintf(v.w * wsc), -1.f), 1.f));
    }
}

// ---------------- RMSNorm + activation quant -> i8 (one block per row, H=2048) ----------------
__global__ __launch_bounds__(256) void rmsq_kernel(const float* __restrict__ x,
                                                   const float* __restrict__ wn,
                                                   int* __restrict__ xq,
                                                   float* __restrict__ xsc) {
    __shared__ float red[256];
    int tid = threadIdx.x;
    const float* xr = x + (size_t)blockIdx.x * HH;
    float4 a = ((const float4*)xr)[tid];
    float4 b = ((const float4*)xr)[tid + 256];
    float s2 = a.x*a.x + a.y*a.y + a.z*a.z + a.w*a.w
             + b.x*b.x + b.y*b.y + b.z*b.z + b.w*b.w;
    red[tid] = s2;
    __syncthreads();
    for (int s = 128; s > 0; s >>= 1) { if (tid < s) red[tid] += red[tid + s]; __syncthreads(); }
    float r = rsqrtf(red[0] * (1.f / HH) + 1e-5f);
    __syncthreads();
    float4 wa = ((const float4*)wn)[tid];
    float4 wb = ((const float4*)wn)[tid + 256];
    float4 na, nb;
    na.x = a.x * r * wa.x; na.y = a.y * r * wa.y; na.z = a.z * r * wa.z; na.w = a.w * r * wa.w;
    nb.x = b.x * r * wb.x; nb.y = b.y * r * wb.y; nb.z = b.z * r * wb.z; nb.w = b.w * r * wb.w;
    float am = fabsf(na.x);
    am = fmaxf(am, fabsf(na.y)); am = fmaxf(am, fabsf(na.z)); am = fmaxf(am, fabsf(na.w));
    am = fmaxf(am, fabsf(nb.x)); am = fmaxf(am, fabsf(nb.y));
    am = fmaxf(am, fabsf(nb.z)); am = fmaxf(am, fabsf(nb.w));
    red[tid] = am;
    __syncthreads();
    for (int s = 128; s > 0; s >>= 1) { if (tid < s) red[tid] = fmaxf(red[tid], red[tid + s]); __syncthreads(); }
    float amax = fmaxf(red[0], 1e-5f);
    float xs = 127.f / amax;
    if (tid == 0) xsc[blockIdx.x] = amax * (1.f / 127.f);
    int* qr = xq + (size_t)blockIdx.x * (HH / 4);
    qr[tid] = packi8(fminf(fmaxf(rintf(na.x * xs), -128.f), 127.f),
                     fminf(fmaxf(rintf(na.y * xs), -128.f), 127.f),
                     fminf(fmaxf(rintf(na.z * xs), -128.f), 127.f),
                     fminf(fmaxf(rintf(na.w * xs), -128.f), 127.f));
    qr[tid + 256] = packi8(fminf(fmaxf(rintf(nb.x * xs), -128.f), 127.f),
                           fminf(fmaxf(rintf(nb.y * xs), -128.f), 127.f),
                           fminf(fmaxf(rintf(nb.z * xs), -128.f), 127.f),
                           fminf(fmaxf(rintf(nb.w * xs), -128.f), 127.f));
}

// ---------------- row absmax quant -> i8 (attention output, H=2048) ----------------
__global__ __launch_bounds__(256) void rowq_kernel(const float* __restrict__ x,
                                                   int* __restrict__ xq,
                                                   float* __restrict__ xsc) {
    __shared__ float red[256];
    int tid = threadIdx.x;
    const float* xr = x + (size_t)blockIdx.x * HH;
    float4 a = ((const float4*)xr)[tid];
    float4 b = ((const float4*)xr)[tid + 256];
    float am = fabsf(a.x);
    am = fmaxf(am, fabsf(a.y)); am = fmaxf(am, fabsf(a.z)); am = fmaxf(am, fabsf(a.w));
    am = fmaxf(am, fabsf(b.x)); am = fmaxf(am, fabsf(b.y));
    am = fmaxf(am, fabsf(b.z)); am = fmaxf(am, fabsf(b.w));
    red[tid] = am;
    __syncthreads();
    for (int s = 128; s > 0; s >>= 1) { if (tid < s) red[tid] = fmaxf(red[tid], red[tid + s]); __syncthreads(); }
    float amax = fmaxf(red[0], 1e-5f);
    float xs = 127.f / amax;
    if (tid == 0) xsc[blockIdx.x] = amax * (1.f / 127.f);
    int* qr = xq + (size_t)blockIdx.x * (HH / 4);
    qr[tid] = packi8(fminf(fmaxf(rintf(a.x * xs), -128.f), 127.f),
                     fminf(fmaxf(rintf(a.y * xs), -128.f), 127.f),
                     fminf(fmaxf(rintf(a.z * xs), -128.f), 127.f),
                     fminf(fmaxf(rintf(a.w * xs), -128.f), 127.f));
    qr[tid + 256] = packi8(fminf(fmaxf(rintf(b.x * xs), -128.f), 127.f),
                           fminf(fmaxf(rintf(b.y * xs), -128.f), 127.f),
                           fminf(fmaxf(rintf(b.z * xs), -128.f), 127.f),
                           fminf(fmaxf(rintf(b.w * xs), -128.f), 127.f));
}

// ---------------- i8 MFMA GEMM (m97 structure, BK=64): C[M,N] = A[M,K]*B[N,K]^T, scaled ----------------
__global__ __launch_bounds__(256) void gemm_i8_kernel(const char* __restrict__ A,
                                                      const char* __restrict__ B,
                                                      float* __restrict__ C,
                                                      const float* __restrict__ rsc,
                                                      const float* __restrict__ wsum,
                                                      float inv_n, int N, int K) {
    __shared__ __align__(16) char Alds[128 * 64];
    __shared__ __align__(16) char Blds[128 * 64];
    int tid = threadIdx.x;
    int lane = tid & 63, w = tid >> 6;
    int quad = lane >> 4, l15 = lane & 15;
    int m0 = blockIdx.y << 7, n0 = blockIdx.x << 7;
    int wm = (w >> 1) << 6, wn = (w & 1) << 6;
    int srow = (w << 5) + (lane >> 2);
    int scol = (lane & 3) << 4;
    const char* Arow = A + (size_t)(m0 + srow) * K + scol;
    const char* Brow = B + (size_t)(n0 + srow) * K + scol;
    char* Adst = &Alds[w << 11];
    char* Bdst = &Blds[w << 11];

    i32x4 acc[4][4] = {};
    for (int k0 = 0; k0 < K; k0 += 64) {
        gl_lds16(Arow + k0, Adst);
        gl_lds16(Arow + (size_t)16 * K + k0, Adst + 1024);
        gl_lds16(Brow + k0, Bdst);
        gl_lds16(Brow + (size_t)16 * K + k0, Bdst + 1024);
        __syncthreads();
        i32x4 af[4], bfr[4];
        #pragma unroll
        for (int i = 0; i < 4; ++i) {
            af[i]  = *(const i32x4*)&Alds[(wm + i * 16 + l15) * 64 + quad * 16];
            bfr[i] = *(const i32x4*)&Blds[(wn + i * 16 + l15) * 64 + quad * 16];
        }
        #pragma unroll
        for (int i = 0; i < 4; ++i)
            #pragma unroll
            for (int j = 0; j < 4; ++j)
                acc[i][j] = __builtin_amdgcn_mfma_i32_16x16x64_i8(af[i], bfr[j], acc[i][j], 0, 0, 0);
        __syncthreads();
    }

    float wsc = fmaxf(wsum[0] * inv_n, 1e-5f);
    #pragma unroll
    for (int i = 0; i < 4; ++i) {
        #pragma unroll
        for (int r = 0; r < 4; ++r) {
            int row = m0 + wm + i * 16 + quad * 4 + r;
            float s = rsc[row] * wsc;
            #pragma unroll
            for (int j = 0; j < 4; ++j) {
                int col = n0 + wn + j * 16 + l15;
                C[(size_t)row * N + col] = (float)acc[i][j][r] * s;
            }
        }
    }
}

// ---------------- QKV i8 GEMM with fused RoPE + fp16 epilogue ----------------
// region: 0..31 -> qh (x0.125), 32..39 -> kh, 40..47 -> vT (packed ushort4).
__global__ __launch_bounds__(256) void gemm_qkv_kernel(const char* __restrict__ A,
                                                       const char* __restrict__ B,
                                                       const float* __restrict__ rsc,
                                                       const float* __restrict__ wsum,
                                                       float inv_n,
                                                       const float* __restrict__ tab,
                                                       ushort* __restrict__ qh,
                                                       ushort* __restrict__ kh,
                                                       ushort* __restrict__ vT) {
    const int K = HH;
    __shared__ __align__(16) char Alds[128 * 64];
    __shared__ __align__(16) char Blds[128 * 64];
    int tid = threadIdx.x;
    int lane = tid & 63, w = tid >> 6;
    int quad = lane >> 4, l15 = lane & 15;
    int m0 = blockIdx.y << 7, n0 = blockIdx.x << 7;
    int wm = (w >> 1) << 6, wn = (w & 1) << 6;
    int srow = (w << 5) + (lane >> 2);
    int scol = (lane & 3) << 4;
    const char* Arow = A + (size_t)(m0 + srow) * K + scol;
    const char* Brow = B + (size_t)(n0 + srow) * K + scol;
    char* Adst = &Alds[w << 11];
    char* Bdst = &Blds[w << 11];

    i32x4 acc[4][4] = {};
    for (int k0 = 0; k0 < K; k0 += 64) {
        gl_lds16(Arow + k0, Adst);
        gl_lds16(Arow + (size_t)16 * K + k0, Adst + 1024);
        gl_lds16(Brow + k0, Bdst);
        gl_lds16(Brow + (size_t)16 * K + k0, Bdst + 1024);
        __syncthreads();
        i32x4 af[4], bfr[4];
        #pragma unroll
        for (int i = 0; i < 4; ++i) {
            af[i]  = *(const i32x4*)&Alds[(wm + i * 16 + l15) * 64 + quad * 16];
            bfr[i] = *(const i32x4*)&Blds[(wn + i * 16 + l15) * 64 + quad * 16];
        }
        #pragma unroll
        for (int i = 0; i < 4; ++i)
            #pragma unroll
            for (int j = 0; j < 4; ++j)
                acc[i][j] = __builtin_amdgcn_mfma_i32_16x16x64_i8(af[i], bfr[j], acc[i][j], 0, 0, 0);
        __syncthreads();
    }

    float wsc = fmaxf(wsum[0] * inv_n, 1e-5f);
    int region = (n0 + wn) >> 6;                 // head index within qkv cols
    if (region < 32) {                           // Q (rope, x0.125)
        #pragma unroll
        for (int i = 0; i < 4; ++i)
            #pragma unroll
            for (int r = 0; r < 4; ++r) {
                int row = m0 + wm + i * 16 + quad * 4 + r;
                float s = rsc[row] * wsc;
                int sp = row & (SS - 1);
                #pragma unroll
                for (int j = 0; j < 2; ++j) {
                    int d = j * 16 + l15;
                    float c = tab[sp * 64 + d], sn = tab[sp * 64 + 32 + d];
                    float xr = (float)acc[i][j][r] * s, xi = (float)acc[i][j + 2][r] * s;
                    qh[(size_t)row * HH + region * 64 + d]      = f2h((xr * c - xi * sn) * 0.125f);
                    qh[(size_t)row * HH + region * 64 + d + 32] = f2h((xr * sn + xi * c) * 0.125f);
                }
            }
    } else if (region < 40) {                    // K (rope)
        int kv = region - 32;
        #pragma unroll
        for (int i = 0; i < 4; ++i)
            #pragma unroll
            for (int r = 0; r < 4; ++r) {
                int row = m0 + wm + i * 16 + quad * 4 + r;
                float s = rsc[row] * wsc;
                int sp = row & (SS - 1);
                #pragma unroll
                for (int j = 0; j < 2; ++j) {
                    int d = j * 16 + l15;
                    float c = tab[sp * 64 + d], sn = tab[sp * 64 + 32 + d];
                    float xr = (float)acc[i][j][r] * s, xi = (float)acc[i][j + 2][r] * s;
                    kh[(size_t)row * (NKV_ * 64) + kv * 64 + d]      = f2h(xr * c - xi * sn);
                    kh[(size_t)row * (NKV_ * 64) + kv * 64 + d + 32] = f2h(xr * sn + xi * c);
                }
            }
    } else {                                     // V -> transposed [b][kv][d][s], packed 4 rows
        int kv = region - 40;
        #pragma unroll
        for (int i = 0; i < 4; ++i) {
            int row0 = m0 + wm + i * 16 + quad * 4;
            int bb = row0 >> 11, sr = row0 & (SS - 1);
            float sc0 = rsc[row0 + 0] * wsc;
            float sc1 = rsc[row0 + 1] * wsc;
            float sc2 = rsc[row0 + 2] * wsc;
            float sc3 = rsc[row0 + 3] * wsc;
            #pragma unroll
            for (int j = 0; j < 4; ++j) {
                int d = j * 16 + l15;
                ushort4 o;
                o.x = f2h((float)acc[i][j][0] * sc0);
                o.y = f2h((float)acc[i][j][1] * sc1);
                o.z = f2h((float)acc[i][j][2] * sc2);
                o.w = f2h((float)acc[i][j][3] * sc3);
                *(ushort4*)&vT[(((size_t)(bb * NKV_ + kv)) * 64 + d) * SS + sr] = o;
            }
        }
    }
}

// ---------------- MFMA flash attention, fixed-max softmax; Ps aliased over Qs ----------------
// Qs is dead after the pre-loop qf register load, and wave w's Ps region == wave w's own
// Q rows (wave-local, program order) -> safe alias. LDS 34.8 -> 26.1 KB = 6 blocks/CU.
__global__ __launch_bounds__(256) void attn_mfma_kernel(const ushort* __restrict__ qh,
                                                        const ushort* __restrict__ kh,
                                                        const ushort* __restrict__ vT,
                                                        float* __restrict__ attno) {
    __shared__ ushort QPs[64 * 68];    // Q: [qrow][d], then per-wave P: [qrow16][t]
    __shared__ ushort Ks[64 * 68];     // [t][d]
    __shared__ ushort Vs[64 * 68];     // [d][t]
    int tid = threadIdx.x;
    int lane = tid & 63, w = tid >> 6;
    int quad = lane >> 4, l15 = lane & 15;
    int s0 = (SS / 64 - 1 - (int)blockIdx.x) << 6;   // longest-first
    int h  = blockIdx.y;
    int b  = blockIdx.z;
    int khd = h >> 2;                   // G = 4

    #pragma unroll
    for (int c = tid; c < 512; c += 256) {
        int r = c >> 3, col = (c & 7) << 3;
        *(uint4*)&QPs[r * 68 + col] =
            *(const uint4*)&qh[((size_t)(b * SS + s0 + r)) * HH + h * 64 + col];
    }
    __syncthreads();
    f16x8 qf[2];
    qf[0] = *(const f16x8*)&QPs[(w * 16 + l15) * 68 + quad * 8];
    qf[1] = *(const f16x8*)&QPs[(w * 16 + l15) * 68 + 32 + quad * 8];
    ushort* Pw = &QPs[w * 1088];        // wave-local P region (aliases own Q rows)

    float lp[4] = {0.f, 0.f, 0.f, 0.f};
    f32x4 of[4] = {};

    for (int t0 = 0; t0 <= s0; t0 += 64) {
        __syncthreads();
        #pragma unroll
        for (int c = tid; c < 512; c += 256) {
            int r = c >> 3, col = (c & 7) << 3;
            *(uint4*)&Ks[r * 68 + col] =
                *(const uint4*)&kh[((size_t)(b * SS + t0 + r)) * (NKV_ * 64) + khd * 64 + col];
            *(uint4*)&Vs[r * 68 + col] =
                *(const uint4*)&vT[(((size_t)(b * NKV_ + khd)) * 64 + r) * SS + t0 + col];
        }
        __syncthreads();

        f32x4 sa[4] = {};
        #pragma unroll
        for (int j = 0; j < 4; ++j) {
            f16x8 kf0 = *(const f16x8*)&Ks[(j * 16 + l15) * 68 + quad * 8];
            f16x8 kf1 = *(const f16x8*)&Ks[(j * 16 + l15) * 68 + 32 + quad * 8];
            sa[j] = __builtin_amdgcn_mfma_f32_16x16x32_f16(qf[0], kf0, sa[j], 0, 0, 0);
            sa[j] = __builtin_amdgcn_mfma_f32_16x16x32_f16(qf[1], kf1, sa[j], 0, 0, 0);
        }

        if (t0 == s0) {                 // causal mask, diagonal tile only
            #pragma unroll
            for (int j = 0; j < 4; ++j) {
                int t = j * 16 + l15;
                #pragma unroll
                for (int r = 0; r < 4; ++r)
                    if (t > w * 16 + quad * 4 + r) sa[j][r] = -INFINITY;
            }
        }

        // fixed-max softmax: p = exp(s); exp(-inf) = 0 handles the mask exactly
        #pragma unroll
        for (int r = 0; r < 4; ++r) {
            float p0 = __expf(sa[0][r]);
            float p1 = __expf(sa[1][r]);
            float p2 = __expf(sa[2][r]);
            float p3 = __expf(sa[3][r]);
            lp[r] += (p0 + p1) + (p2 + p3);
            int prow = (quad * 4 + r) * 68 + l15;
            Pw[prow]      = f2h(p0);
            Pw[prow + 16] = f2h(p1);
            Pw[prow + 32] = f2h(p2);
            Pw[prow + 48] = f2h(p3);
        }

        f16x8 pf0 = *(const f16x8*)&Pw[l15 * 68 + quad * 8];
        f16x8 pf1 = *(const f16x8*)&Pw[l15 * 68 + 32 + quad * 8];
        #pragma unroll
        for (int j = 0; j < 4; ++j) {
            f16x8 vf0 = *(const f16x8*)&Vs[(j * 16 + l15) * 68 + quad * 8];
            f16x8 vf1 = *(const f16x8*)&Vs[(j * 16 + l15) * 68 + 32 + quad * 8];
            of[j] = __builtin_amdgcn_mfma_f32_16x16x32_f16(pf0, vf0, of[j], 0, 0, 0);
            of[j] = __builtin_amdgcn_mfma_f32_16x16x32_f16(pf1, vf1, of[j], 0, 0, 0);
        }
    }

    #pragma unroll
    for (int r = 0; r < 4; ++r) {
        float lr = lp[r];
        lr += __shfl_xor(lr, 1, 64);
        lr += __shfl_xor(lr, 2, 64);
        lr += __shfl_xor(lr, 4, 64);
        lr += __shfl_xor(lr, 8, 64);
        int row = s0 + w * 16 + quad * 4 + r;
        float inv = 1.f / lr;
        #pragma unroll
        for (int j = 0; j < 4; ++j)
            attno[((size_t)(b * SS + row)) * HH + h * 64 + j * 16 + l15] = of[j][r] * inv;
    }
}

extern "C" void kernel_launch(void* const* d_in, const int* in_sizes, int n_in,
                              void* d_out, int out_size, void* d_ws, size_t ws_size,
                              hipStream_t stream) {
    const float* x      = (const float*)d_in[0];
    const float* w_norm = (const float*)d_in[1];
    const float* w_qkv  = (const float*)d_in[2];
    const float* w_out  = (const float*)d_in[3];
    float* out = (float*)d_out;
    char* ws = (char*)d_ws;

    float*  scal  = (float*)(ws + 0);           // [0]=sum|w_qkv|, [1]=sum|w_out|
    float*  rope  = (float*)(ws + 64);          // 2048*64 f32, ends 524352
    char*   xq    = (char*)(ws + 524352);       // 4096*2048 i8, ends 8912960
    float*  xsc   = (float*)(ws + 8912960);     // 4096 f32, ends 8929344
    char*   wq1   = (char*)(ws + 8929344);      // 3072*2048 i8, ends 15220800
    char*   wq2   = (char*)(ws + 15220800);     // 2048*2048 i8, ends 19415104
    ushort* qh    = (ushort*)(ws + 19415104);   // 4096*2048 f16, ends 36192320
    ushort* kh    = (ushort*)(ws + 36192320);   // 4096*512 f16, ends 40386624
    ushort* vT    = (ushort*)(ws + 40386624);   // 2*8*64*2048 f16, ends 44580928
    float*  attno = (float*)(ws + 44580928);    // 4096*2048 f32, ends 78135360

    hipMemsetAsync(scal, 0, 64, stream);
    prep_kernel<<<2816, 256, 0, stream>>>(w_qkv, w_out, scal, rope);
    wquant_kernel<<<2560, 256, 0, stream>>>(w_qkv, w_out, (int*)wq1, (int*)wq2, scal);
    rmsq_kernel<<<MTOK, 256, 0, stream>>>(x, w_norm, (int*)xq, xsc);
    gemm_qkv_kernel<<<dim3(QKVO / 128, MTOK / 128), 256, 0, stream>>>(xq, wq1, xsc, scal + 0,
                                                                      1.0f / 6291456.0f, rope,
                                                                      qh, kh, vT);
    attn_mfma_kernel<<<dim3(SS / 64, NH_, 2), 256, 0, stream>>>(qh, kh, vT, attno);
    rowq_kernel<<<MTOK, 256, 0, stream>>>(attno, (int*)xq, xsc);
    gemm_i8_kernel<<<dim3(HH / 128, MTOK / 128), 256, 0, stream>>>(xq, wq2, out, xsc, scal + 1,
                                                                   1.0f / 4194304.0f, HH, HH);
}

// Round 11
// 396.622 us; speedup vs baseline: 1.0613x; 1.0613x over previous
//
#include <hip/hip_runtime.h>
#include <math.h>

#define SS   2048
#define HH   2048
#define NH_  32
#define NKV_ 8
#define HD_  64
#define QKVO 3072     // (32 + 2*8) * 64
#define MTOK 4096     // B * S

typedef _Float16 f16x8 __attribute__((ext_vector_type(8)));   // 8 fp16 in 4 VGPRs
typedef float f32x4 __attribute__((ext_vector_type(4)));
typedef int   i32x4 __attribute__((ext_vector_type(4)));      // 16 i8 (A/B frag) or 4 i32 (C/D)

__device__ inline ushort f2h(float f) {
    _Float16 h = (_Float16)f;
    return *(ushort*)&h;
}
__device__ inline int packi8(float a, float b, float c, float d) {   // values are exact ints
    return ((int)a & 255) | (((int)b & 255) << 8) | (((int)c & 255) << 16) | (((int)d & 255) << 24);
}

__device__ inline void gl_lds16(const void* g, void* l) {
    __builtin_amdgcn_global_load_lds((const __attribute__((address_space(1))) void*)g,
                                     (__attribute__((address_space(3))) void*)l, 16, 0, 0);
}

// ---------------- fused prologue: |w| sums (float4) + rope table ----------------
__global__ __launch_bounds__(256) void prep_kernel(const float* __restrict__ wq,
                                                   const float* __restrict__ wo,
                                                   float* __restrict__ scal,
                                                   float* __restrict__ tab) {
    __shared__ float red[256];
    int bx = blockIdx.x, tid = threadIdx.x;
    if (bx < 2560) {
        const float* src; float* dst; int n4, b0, nb;
        if (bx < 1536) { src = wq; dst = scal + 0; n4 = QKVO * HH / 4; b0 = bx;        nb = 1536; }
        else           { src = wo; dst = scal + 1; n4 = HH * HH / 4;   b0 = bx - 1536; nb = 1024; }
        float acc = 0.f;
        for (int i = b0 * 256 + tid; i < n4; i += nb * 256) {
            float4 v = ((const float4*)src)[i];
            acc += (fabsf(v.x) + fabsf(v.y)) + (fabsf(v.z) + fabsf(v.w));
        }
        red[tid] = acc;
        __syncthreads();
        for (int s = 128; s > 0; s >>= 1) { if (tid < s) red[tid] += red[tid + s]; __syncthreads(); }
        if (tid == 0) atomicAdd(dst, red[0]);
    } else {
        int i = (bx - 2560) * 256 + tid;        // SS*32 threads
        int sp = i >> 5, d = i & 31;
        float inv = (float)pow(10000.0, -(double)d / 32.0);
        float ang = (float)sp * inv;
        tab[sp * 64 + d]      = cosf(ang);
        tab[sp * 64 + 32 + d] = sinf(ang);
    }
}

// ---------------- fused ternary weight quant -> i8 (both weights) ----------------
__global__ __launch_bounds__(256) void wquant_kernel(const float* __restrict__ wq,
                                                     const float* __restrict__ wo,
                                                     int* __restrict__ q1,
                                                     int* __restrict__ q2,
                                                     const float* __restrict__ scal) {
    int bx = blockIdx.x, tid = threadIdx.x;
    const float* src; int* dst; int n4, b0, nb; float mean;
    if (bx < 1536) { src = wq; dst = q1; n4 = QKVO * HH / 4; b0 = bx;        nb = 1536;
                     mean = fmaxf(scal[0] * (1.0f / 6291456.0f), 1e-5f); }
    else           { src = wo; dst = q2; n4 = HH * HH / 4;   b0 = bx - 1536; nb = 1024;
                     mean = fmaxf(scal[1] * (1.0f / 4194304.0f), 1e-5f); }
    float wsc = 1.f / mean;
    for (int i = b0 * 256 + tid; i < n4; i += nb * 256) {
        float4 v = ((const float4*)src)[i];
        dst[i] = packi8(fminf(fmaxf(rintf(v.x * wsc), -1.f), 1.f),
                        fminf(fmaxf(rintf(v.y * wsc), -1.f), 1.f),
                        fminf(fmaxf(rintf(v.z * wsc), -1.f), 1.f),
                        fminf(fmaxf(rintf(v.w * wsc), -1.f), 1.f));
    }
}

// ---------------- RMSNorm + activation quant -> i8 (one block per row, H=2048) ----------------
__global__ __launch_bounds__(256) void rmsq_kernel(const float* __restrict__ x,
                                                   const float* __restrict__ wn,
                                                   int* __restrict__ xq,
                                                   float* __restrict__ xsc) {
    __shared__ float red[256];
    int tid = threadIdx.x;
    const float* xr = x + (size_t)blockIdx.x * HH;
    float4 a = ((const float4*)xr)[tid];
    float4 b = ((const float4*)xr)[tid + 256];
    float s2 = a.x*a.x + a.y*a.y + a.z*a.z + a.w*a.w
             + b.x*b.x + b.y*b.y + b.z*b.z + b.w*b.w;
    red[tid] = s2;
    __syncthreads();
    for (int s = 128; s > 0; s >>= 1) { if (tid < s) red[tid] += red[tid + s]; __syncthreads(); }
    float r = rsqrtf(red[0] * (1.f / HH) + 1e-5f);
    __syncthreads();
    float4 wa = ((const float4*)wn)[tid];
    float4 wb = ((const float4*)wn)[tid + 256];
    float4 na, nb;
    na.x = a.x * r * wa.x; na.y = a.y * r * wa.y; na.z = a.z * r * wa.z; na.w = a.w * r * wa.w;
    nb.x = b.x * r * wb.x; nb.y = b.y * r * wb.y; nb.z = b.z * r * wb.z; nb.w = b.w * r * wb.w;
    float am = fabsf(na.x);
    am = fmaxf(am, fabsf(na.y)); am = fmaxf(am, fabsf(na.z)); am = fmaxf(am, fabsf(na.w));
    am = fmaxf(am, fabsf(nb.x)); am = fmaxf(am, fabsf(nb.y));
    am = fmaxf(am, fabsf(nb.z)); am = fmaxf(am, fabsf(nb.w));
    red[tid] = am;
    __syncthreads();
    for (int s = 128; s > 0; s >>= 1) { if (tid < s) red[tid] = fmaxf(red[tid], red[tid + s]); __syncthreads(); }
    float amax = fmaxf(red[0], 1e-5f);
    float xs = 127.f / amax;
    if (tid == 0) xsc[blockIdx.x] = amax * (1.f / 127.f);
    int* qr = xq + (size_t)blockIdx.x * (HH / 4);
    qr[tid] = packi8(fminf(fmaxf(rintf(na.x * xs), -128.f), 127.f),
                     fminf(fmaxf(rintf(na.y * xs), -128.f), 127.f),
                     fminf(fmaxf(rintf(na.z * xs), -128.f), 127.f),
                     fminf(fmaxf(rintf(na.w * xs), -128.f), 127.f));
    qr[tid + 256] = packi8(fminf(fmaxf(rintf(nb.x * xs), -128.f), 127.f),
                           fminf(fmaxf(rintf(nb.y * xs), -128.f), 127.f),
                           fminf(fmaxf(rintf(nb.z * xs), -128.f), 127.f),
                           fminf(fmaxf(rintf(nb.w * xs), -128.f), 127.f));
}

// ---------------- row absmax quant -> i8 (attention output, H=2048) ----------------
__global__ __launch_bounds__(256) void rowq_kernel(const float* __restrict__ x,
                                                   int* __restrict__ xq,
                                                   float* __restrict__ xsc) {
    __shared__ float red[256];
    int tid = threadIdx.x;
    const float* xr = x + (size_t)blockIdx.x * HH;
    float4 a = ((const float4*)xr)[tid];
    float4 b = ((const float4*)xr)[tid + 256];
    float am = fabsf(a.x);
    am = fmaxf(am, fabsf(a.y)); am = fmaxf(am, fabsf(a.z)); am = fmaxf(am, fabsf(a.w));
    am = fmaxf(am, fabsf(b.x)); am = fmaxf(am, fabsf(b.y));
    am = fmaxf(am, fabsf(b.z)); am = fmaxf(am, fabsf(b.w));
    red[tid] = am;
    __syncthreads();
    for (int s = 128; s > 0; s >>= 1) { if (tid < s) red[tid] = fmaxf(red[tid], red[tid + s]); __syncthreads(); }
    float amax = fmaxf(red[0], 1e-5f);
    float xs = 127.f / amax;
    if (tid == 0) xsc[blockIdx.x] = amax * (1.f / 127.f);
    int* qr = xq + (size_t)blockIdx.x * (HH / 4);
    qr[tid] = packi8(fminf(fmaxf(rintf(a.x * xs), -128.f), 127.f),
                     fminf(fmaxf(rintf(a.y * xs), -128.f), 127.f),
                     fminf(fmaxf(rintf(a.z * xs), -128.f), 127.f),
                     fminf(fmaxf(rintf(a.w * xs), -128.f), 127.f));
    qr[tid + 256] = packi8(fminf(fmaxf(rintf(b.x * xs), -128.f), 127.f),
                           fminf(fmaxf(rintf(b.y * xs), -128.f), 127.f),
                           fminf(fmaxf(rintf(b.z * xs), -128.f), 127.f),
                           fminf(fmaxf(rintf(b.w * xs), -128.f), 127.f));
}

// ---------------- i8 MFMA GEMM, BK=128, XOR-swizzled (conflict-free frag reads) ----------------
// Lane stages global chunk (lane&7)^(lane>>3) of its row -> LDS position lane&7;
// frag read for k-chunk c at position c^(row&7): 2-way banks (free). 16 iters, 32 MFMA/barrier.
__global__ __launch_bounds__(256) void gemm_i8_kernel(const char* __restrict__ A,
                                                      const char* __restrict__ B,
                                                      float* __restrict__ C,
                                                      const float* __restrict__ rsc,
                                                      const float* __restrict__ wsum,
                                                      float inv_n, int N, int K) {
    __shared__ __align__(16) char Alds[128 * 128];
    __shared__ __align__(16) char Blds[128 * 128];
    int tid = threadIdx.x;
    int lane = tid & 63, w = tid >> 6;
    int quad = lane >> 4, l15 = lane & 15;
    int m0 = blockIdx.y << 7, n0 = blockIdx.x << 7;
    int wm = (w >> 1) << 6, wn = (w & 1) << 6;
    int srow = (w << 5) + (lane >> 3);            // + i*8 per staging instr
    int scol = ((lane & 7) ^ (lane >> 3)) << 4;   // XOR swizzle (row&7 == lane>>3)
    const char* Arow = A + (size_t)(m0 + srow) * K + scol;
    const char* Brow = B + (size_t)(n0 + srow) * K + scol;
    char* Adst = &Alds[w << 12];                  // 4096 B per wave
    char* Bdst = &Blds[w << 12];

    i32x4 acc[4][4] = {};
    for (int k0 = 0; k0 < K; k0 += 128) {
        #pragma unroll
        for (int i = 0; i < 4; ++i) {
            gl_lds16(Arow + (size_t)(i * 8) * K + k0, Adst + i * 1024);
            gl_lds16(Brow + (size_t)(i * 8) * K + k0, Bdst + i * 1024);
        }
        __syncthreads();
        #pragma unroll
        for (int ks = 0; ks < 2; ++ks) {
            i32x4 af[4], bfr[4];
            #pragma unroll
            for (int i = 0; i < 4; ++i) {
                int ra = wm + i * 16 + l15;       // ra&7 == l15&7
                int ca = ((ks * 4 + quad) ^ (l15 & 7)) << 4;
                af[i]  = *(const i32x4*)&Alds[ra * 128 + ca];
                bfr[i] = *(const i32x4*)&Blds[(wn + i * 16 + l15) * 128 + ca];
            }
            #pragma unroll
            for (int i = 0; i < 4; ++i)
                #pragma unroll
                for (int j = 0; j < 4; ++j)
                    acc[i][j] = __builtin_amdgcn_mfma_i32_16x16x64_i8(af[i], bfr[j], acc[i][j], 0, 0, 0);
        }
        __syncthreads();
    }

    float wsc = fmaxf(wsum[0] * inv_n, 1e-5f);
    #pragma unroll
    for (int i = 0; i < 4; ++i) {
        #pragma unroll
        for (int r = 0; r < 4; ++r) {
            int row = m0 + wm + i * 16 + quad * 4 + r;
            float s = rsc[row] * wsc;
            #pragma unroll
            for (int j = 0; j < 4; ++j) {
                int col = n0 + wn + j * 16 + l15;
                C[(size_t)row * N + col] = (float)acc[i][j][r] * s;
            }
        }
    }
}

// ---------------- QKV i8 GEMM (BK=128 swizzled) with fused RoPE + fp16 epilogue ----------------
__global__ __launch_bounds__(256) void gemm_qkv_kernel(const char* __restrict__ A,
                                                       const char* __restrict__ B,
                                                       const float* __restrict__ rsc,
                                                       const float* __restrict__ wsum,
                                                       float inv_n,
                                                       const float* __restrict__ tab,
                                                       ushort* __restrict__ qh,
                                                       ushort* __restrict__ kh,
                                                       ushort* __restrict__ vT) {
    const int K = HH;
    __shared__ __align__(16) char Alds[128 * 128];
    __shared__ __align__(16) char Blds[128 * 128];
    int tid = threadIdx.x;
    int lane = tid & 63, w = tid >> 6;
    int quad = lane >> 4, l15 = lane & 15;
    int m0 = blockIdx.y << 7, n0 = blockIdx.x << 7;
    int wm = (w >> 1) << 6, wn = (w & 1) << 6;
    int srow = (w << 5) + (lane >> 3);
    int scol = ((lane & 7) ^ (lane >> 3)) << 4;
    const char* Arow = A + (size_t)(m0 + srow) * K + scol;
    const char* Brow = B + (size_t)(n0 + srow) * K + scol;
    char* Adst = &Alds[w << 12];
    char* Bdst = &Blds[w << 12];

    i32x4 acc[4][4] = {};
    for (int k0 = 0; k0 < K; k0 += 128) {
        #pragma unroll
        for (int i = 0; i < 4; ++i) {
            gl_lds16(Arow + (size_t)(i * 8) * K + k0, Adst + i * 1024);
            gl_lds16(Brow + (size_t)(i * 8) * K + k0, Bdst + i * 1024);
        }
        __syncthreads();
        #pragma unroll
        for (int ks = 0; ks < 2; ++ks) {
            i32x4 af[4], bfr[4];
            #pragma unroll
            for (int i = 0; i < 4; ++i) {
                int ca = ((ks * 4 + quad) ^ (l15 & 7)) << 4;
                af[i]  = *(const i32x4*)&Alds[(wm + i * 16 + l15) * 128 + ca];
                bfr[i] = *(const i32x4*)&Blds[(wn + i * 16 + l15) * 128 + ca];
            }
            #pragma unroll
            for (int i = 0; i < 4; ++i)
                #pragma unroll
                for (int j = 0; j < 4; ++j)
                    acc[i][j] = __builtin_amdgcn_mfma_i32_16x16x64_i8(af[i], bfr[j], acc[i][j], 0, 0, 0);
        }
        __syncthreads();
    }

    float wsc = fmaxf(wsum[0] * inv_n, 1e-5f);
    int region = (n0 + wn) >> 6;                 // head index within qkv cols
    if (region < 32) {                           // Q (rope, x0.125)
        #pragma unroll
        for (int i = 0; i < 4; ++i)
            #pragma unroll
            for (int r = 0; r < 4; ++r) {
                int row = m0 + wm + i * 16 + quad * 4 + r;
                float s = rsc[row] * wsc;
                int sp = row & (SS - 1);
                #pragma unroll
                for (int j = 0; j < 2; ++j) {
                    int d = j * 16 + l15;
                    float c = tab[sp * 64 + d], sn = tab[sp * 64 + 32 + d];
                    float xr = (float)acc[i][j][r] * s, xi = (float)acc[i][j + 2][r] * s;
                    qh[(size_t)row * HH + region * 64 + d]      = f2h((xr * c - xi * sn) * 0.125f);
                    qh[(size_t)row * HH + region * 64 + d + 32] = f2h((xr * sn + xi * c) * 0.125f);
                }
            }
    } else if (region < 40) {                    // K (rope)
        int kv = region - 32;
        #pragma unroll
        for (int i = 0; i < 4; ++i)
            #pragma unroll
            for (int r = 0; r < 4; ++r) {
                int row = m0 + wm + i * 16 + quad * 4 + r;
                float s = rsc[row] * wsc;
                int sp = row & (SS - 1);
                #pragma unroll
                for (int j = 0; j < 2; ++j) {
                    int d = j * 16 + l15;
                    float c = tab[sp * 64 + d], sn = tab[sp * 64 + 32 + d];
                    float xr = (float)acc[i][j][r] * s, xi = (float)acc[i][j + 2][r] * s;
                    kh[(size_t)row * (NKV_ * 64) + kv * 64 + d]      = f2h(xr * c - xi * sn);
                    kh[(size_t)row * (NKV_ * 64) + kv * 64 + d + 32] = f2h(xr * sn + xi * c);
                }
            }
    } else {                                     // V -> transposed [b][kv][d][s], packed 4 rows
        int kv = region - 40;
        #pragma unroll
        for (int i = 0; i < 4; ++i) {
            int row0 = m0 + wm + i * 16 + quad * 4;
            int bb = row0 >> 11, sr = row0 & (SS - 1);
            float sc0 = rsc[row0 + 0] * wsc;
            float sc1 = rsc[row0 + 1] * wsc;
            float sc2 = rsc[row0 + 2] * wsc;
            float sc3 = rsc[row0 + 3] * wsc;
            #pragma unroll
            for (int j = 0; j < 4; ++j) {
                int d = j * 16 + l15;
                ushort4 o;
                o.x = f2h((float)acc[i][j][0] * sc0);
                o.y = f2h((float)acc[i][j][1] * sc1);
                o.z = f2h((float)acc[i][j][2] * sc2);
                o.w = f2h((float)acc[i][j][3] * sc3);
                *(ushort4*)&vT[(((size_t)(bb * NKV_ + kv)) * 64 + d) * SS + sr] = o;
            }
        }
    }
}

// ---------------- MFMA flash attention, fixed-max softmax (R8 config verbatim: 157 us) ----------------
__global__ __launch_bounds__(256) void attn_mfma_kernel(const ushort* __restrict__ qh,
                                                        const ushort* __restrict__ kh,
                                                        const ushort* __restrict__ vT,
                                                        float* __restrict__ attno) {
    __shared__ ushort Qs[64 * 68];     // [qrow][d]
    __shared__ ushort Ks[64 * 68];     // [t][d]
    __shared__ ushort Vs[64 * 68];     // [d][t]
    __shared__ ushort Ps[4][16 * 68];  // per-wave [qrow16][t]
    int tid = threadIdx.x;
    int lane = tid & 63, w = tid >> 6;
    int quad = lane >> 4, l15 = lane & 15;
    int s0 = (SS / 64 - 1 - (int)blockIdx.x) << 6;   // longest-first
    int h  = blockIdx.y;
    int b  = blockIdx.z;
    int khd = h >> 2;                   // G = 4

    #pragma unroll
    for (int c = tid; c < 512; c += 256) {
        int r = c >> 3, col = (c & 7) << 3;
        *(uint4*)&Qs[r * 68 + col] =
            *(const uint4*)&qh[((size_t)(b * SS + s0 + r)) * HH + h * 64 + col];
    }
    __syncthreads();
    f16x8 qf[2];
    qf[0] = *(const f16x8*)&Qs[(w * 16 + l15) * 68 + quad * 8];
    qf[1] = *(const f16x8*)&Qs[(w * 16 + l15) * 68 + 32 + quad * 8];

    float lp[4] = {0.f, 0.f, 0.f, 0.f};
    f32x4 of[4] = {};

    for (int t0 = 0; t0 <= s0; t0 += 64) {
        __syncthreads();
        #pragma unroll
        for (int c = tid; c < 512; c += 256) {
            int r = c >> 3, col = (c & 7) << 3;
            *(uint4*)&Ks[r * 68 + col] =
                *(const uint4*)&kh[((size_t)(b * SS + t0 + r)) * (NKV_ * 64) + khd * 64 + col];
            *(uint4*)&Vs[r * 68 + col] =
                *(const uint4*)&vT[(((size_t)(b * NKV_ + khd)) * 64 + r) * SS + t0 + col];
        }
        __syncthreads();

        f32x4 sa[4] = {};
        #pragma unroll
        for (int j = 0; j < 4; ++j) {
            f16x8 kf0 = *(const f16x8*)&Ks[(j * 16 + l15) * 68 + quad * 8];
            f16x8 kf1 = *(const f16x8*)&Ks[(j * 16 + l15) * 68 + 32 + quad * 8];
            sa[j] = __builtin_amdgcn_mfma_f32_16x16x32_f16(qf[0], kf0, sa[j], 0, 0, 0);
            sa[j] = __builtin_amdgcn_mfma_f32_16x16x32_f16(qf[1], kf1, sa[j], 0, 0, 0);
        }

        if (t0 == s0) {                 // causal mask, diagonal tile only
            #pragma unroll
            for (int j = 0; j < 4; ++j) {
                int t = j * 16 + l15;
                #pragma unroll
                for (int r = 0; r < 4; ++r)
                    if (t > w * 16 + quad * 4 + r) sa[j][r] = -INFINITY;
            }
        }

        #pragma unroll
        for (int r = 0; r < 4; ++r) {
            float p0 = __expf(sa[0][r]);
            float p1 = __expf(sa[1][r]);
            float p2 = __expf(sa[2][r]);
            float p3 = __expf(sa[3][r]);
            lp[r] += (p0 + p1) + (p2 + p3);
            int prow = (quad * 4 + r) * 68 + l15;
            Ps[w][prow]      = f2h(p0);
            Ps[w][prow + 16] = f2h(p1);
            Ps[w][prow + 32] = f2h(p2);
            Ps[w][prow + 48] = f2h(p3);
        }

        f16x8 pf0 = *(const f16x8*)&Ps[w][l15 * 68 + quad * 8];
        f16x8 pf1 = *(const f16x8*)&Ps[w][l15 * 68 + 32 + quad * 8];
        #pragma unroll
        for (int j = 0; j < 4; ++j) {
            f16x8 vf0 = *(const f16x8*)&Vs[(j * 16 + l15) * 68 + quad * 8];
            f16x8 vf1 = *(const f16x8*)&Vs[(j * 16 + l15) * 68 + 32 + quad * 8];
            of[j] = __builtin_amdgcn_mfma_f32_16x16x32_f16(pf0, vf0, of[j], 0, 0, 0);
            of[j] = __builtin_amdgcn_mfma_f32_16x16x32_f16(pf1, vf1, of[j], 0, 0, 0);
        }
    }

    #pragma unroll
    for (int r = 0; r < 4; ++r) {
        float lr = lp[r];
        lr += __shfl_xor(lr, 1, 64);
        lr += __shfl_xor(lr, 2, 64);
        lr += __shfl_xor(lr, 4, 64);
        lr += __shfl_xor(lr, 8, 64);
        int row = s0 + w * 16 + quad * 4 + r;
        float inv = 1.f / lr;
        #pragma unroll
        for (int j = 0; j < 4; ++j)
            attno[((size_t)(b * SS + row)) * HH + h * 64 + j * 16 + l15] = of[j][r] * inv;
    }
}

extern "C" void kernel_launch(void* const* d_in, const int* in_sizes, int n_in,
                              void* d_out, int out_size, void* d_ws, size_t ws_size,
                              hipStream_t stream) {
    const float* x      = (const float*)d_in[0];
    const float* w_norm = (const float*)d_in[1];
    const float* w_qkv  = (const float*)d_in[2];
    const float* w_out  = (const float*)d_in[3];
    float* out = (float*)d_out;
    char* ws = (char*)d_ws;

    float*  scal  = (float*)(ws + 0);           // [0]=sum|w_qkv|, [1]=sum|w_out|
    float*  rope  = (float*)(ws + 64);          // 2048*64 f32, ends 524352
    char*   xq    = (char*)(ws + 524352);       // 4096*2048 i8, ends 8912960
    float*  xsc   = (float*)(ws + 8912960);     // 4096 f32, ends 8929344
    char*   wq1   = (char*)(ws + 8929344);      // 3072*2048 i8, ends 15220800
    char*   wq2   = (char*)(ws + 15220800);     // 2048*2048 i8, ends 19415104
    ushort* qh    = (ushort*)(ws + 19415104);   // 4096*2048 f16, ends 36192320
    ushort* kh    = (ushort*)(ws + 36192320);   // 4096*512 f16, ends 40386624
    ushort* vT    = (ushort*)(ws + 40386624);   // 2*8*64*2048 f16, ends 44580928
    float*  attno = (float*)(ws + 44580928);    // 4096*2048 f32, ends 78135360

    hipMemsetAsync(scal, 0, 64, stream);
    prep_kernel<<<2816, 256, 0, stream>>>(w_qkv, w_out, scal, rope);
    wquant_kernel<<<2560, 256, 0, stream>>>(w_qkv, w_out, (int*)wq1, (int*)wq2, scal);
    rmsq_kernel<<<MTOK, 256, 0, stream>>>(x, w_norm, (int*)xq, xsc);
    gemm_qkv_kernel<<<dim3(QKVO / 128, MTOK / 128), 256, 0, stream>>>(xq, wq1, xsc, scal + 0,
                                                                      1.0f / 6291456.0f, rope,
                                                                      qh, kh, vT);
    attn_mfma_kernel<<<dim3(SS / 64, NH_, 2), 256, 0, stream>>>(qh, kh, vT, attno);
    rowq_kernel<<<MTOK, 256, 0, stream>>>(attno, (int*)xq, xsc);
    gemm_i8_kernel<<<dim3(HH / 128, MTOK / 128), 256, 0, stream>>>(xq, wq2, out, xsc, scal + 1,
                                                                   1.0f / 4194304.0f, HH, HH);
}